// Round 14
// baseline (364.815 us; speedup 1.0000x reference)
//
#include <hip/hip_runtime.h>
#include <hip/hip_bf16.h>
#include <cstdint>
#include <cstddef>

#define B_ 4
#define S_ 1024
#define V_ 32000
#define D_ 256
#define H_ 8
#define DH_ 32
#define L_ 4
#define MROWS (B_*S_)

typedef __attribute__((ext_vector_type(8))) short bf16x8;
typedef __attribute__((ext_vector_type(4))) float f32x4;

__device__ __forceinline__ unsigned short f2bf(float f) {
  union { float f; unsigned u; } c; c.f = f;
  unsigned u = c.u;
  u += 0x7fff + ((u >> 16) & 1);   // round-to-nearest-even
  return (unsigned short)(u >> 16);
}
__device__ __forceinline__ float bf2f(unsigned short u) {
  union { unsigned u; float f; } c; c.u = ((unsigned)u) << 16; return c.f;
}

// async global->LDS, 16B per lane; LDS dest is wave-uniform base + lane*16
__device__ __forceinline__ void gload16(const unsigned short* g, unsigned short* l) {
  __builtin_amdgcn_global_load_lds(
      (const __attribute__((address_space(1))) void*)g,
      (__attribute__((address_space(3))) void*)l, 16, 0, 0);
}

// ---- XOR-swizzled LDS tiles: lds[row][inner ^ ((row&7)<<4)] = g[row][inner]
template<int BM, int BK, int NW>
__device__ __forceinline__ void stage_tile_swz(const unsigned short* __restrict__ g, int ldg,
                                               unsigned short* lds, int wave, int lane) {
  constexpr int CH  = BM * BK * 2 / 1024;   // 1KB chunks
  constexpr int BKB = BK * 2;               // bytes per row
#pragma unroll
  for (int t = 0; t < CH / NW; ++t) {
    int c = wave + t * NW;
    int byte  = c * 1024 + lane * 16;
    int row   = byte / BKB;
    int inner = (byte % BKB) ^ ((row & 7) << 4);
    gload16(g + (size_t)row * ldg + (inner >> 1), lds + c * 512);
  }
}

// swizzled 16B fragment read: row-major [*][BKB/2] tile, kbytes multiple of 16
template<int BKB>
__device__ __forceinline__ bf16x8 lds_frag(const unsigned short* base, int row, int kbytes) {
  int b = (row * BKB + kbytes) ^ ((row & 7) << 4);
  return *(const bf16x8*)((const char*)base + b);
}

// ---------------- embed + LN(layer0) + dual-layout emit ----------------
__global__ __launch_bounds__(512) void k_embln(
    const int* __restrict__ X, const float* __restrict__ emb,
    const float* __restrict__ lng, const float* __restrict__ lnb,
    float* __restrict__ x, unsigned short* __restrict__ xbf,
    unsigned short* __restrict__ xnT) {
  __shared__ __align__(16) float xf[16][264];
  __shared__ float mrow[16], rrow[16];
  int r0 = blockIdx.x * 16;
  int tid = threadIdx.x;
  int w = tid >> 6, lane = tid & 63;
#pragma unroll
  for (int rr = 0; rr < 2; rr++) {
    int row = w * 2 + rr; int grow = r0 + row;
    int tok = X[grow];
    f32x4 v = *(const f32x4*)(emb + (size_t)tok * D_ + lane * 4);
    *(f32x4*)(x + (size_t)grow * D_ + lane * 4) = v;
    *(f32x4*)&xf[row][lane * 4] = v;
    float s = v[0] + v[1] + v[2] + v[3];
    float ss = v[0]*v[0] + v[1]*v[1] + v[2]*v[2] + v[3]*v[3];
#pragma unroll
    for (int off = 1; off < 64; off <<= 1) {
      s  += __shfl_xor(s, off, 64);
      ss += __shfl_xor(ss, off, 64);
    }
    float mean = s * (1.f / D_);
    float var = ss * (1.f / D_) - mean * mean;
    float rinv = rsqrtf(var + 1e-5f);
    float4 g4 = *(const float4*)(lng + lane * 4);
    float4 b4 = *(const float4*)(lnb + lane * 4);
    ushort4 o;
    o.x = f2bf((v[0] - mean) * rinv * g4.x + b4.x);
    o.y = f2bf((v[1] - mean) * rinv * g4.y + b4.y);
    o.z = f2bf((v[2] - mean) * rinv * g4.z + b4.z);
    o.w = f2bf((v[3] - mean) * rinv * g4.w + b4.w);
    *(ushort4*)(xbf + (size_t)grow * D_ + lane * 4) = o;
    if (lane == 0) { mrow[row] = mean; rrow[row] = rinv; }
  }
  __syncthreads();
  int d = tid & 255, half = tid >> 8;
  float gd = lng[d], bd = lnb[d];
  int bb = r0 >> 10, s0 = r0 & 1023;
  bf16x8 o8;
#pragma unroll
  for (int k = 0; k < 8; k++) {
    int srow = half * 8 + k;
    o8[k] = (short)f2bf((xf[srow][d] - mrow[srow]) * rrow[srow] * gd + bd);
  }
  *(bf16x8*)(xnT + ((size_t)(bb * 256 + d)) * S_ + s0 + half * 8) = o8;
}

// ---------------- fused layer: MFMA attention + 3-GEMM MLP + residual + next LN ----
template<int LAST>
__global__ __launch_bounds__(512) void k_layer(
    const unsigned short* __restrict__ xbf,   // layer input  [4096][256] bf16
    const unsigned short* __restrict__ xnT,   // layer input  [4][256][1024] bf16
    const float* __restrict__ WQ, const float* __restrict__ WK,
    const float* __restrict__ WV, const float* __restrict__ Om,
    const unsigned short* __restrict__ Wl,    // 3 x [256][256] bf16 (this layer)
    const float* __restrict__ b1, const float* __restrict__ b2, const float* __restrict__ b3,
    float* __restrict__ x,                    // residual f32
    const float* __restrict__ lngN, const float* __restrict__ lnbN,
    unsigned short* __restrict__ xbfN, unsigned short* __restrict__ xnTN,  // outputs (!LAST)
    unsigned short* __restrict__ actB,        // output (LAST)
    int layer) {
  __shared__ __align__(16) unsigned short P_lds[8][16][72];
  __shared__ __align__(16) unsigned short Aa[16 * 256];
  __shared__ __align__(16) unsigned short Ab[16 * 256];
  __shared__ __align__(16) unsigned short Ab2[16 * 256];
  __shared__ __align__(16) unsigned short Bp[2][256 * 64];
  __shared__ __align__(16) float xf[16][264];
  __shared__ float mrow[16], rrow[16];

  int b = blockIdx.x >> 6;
  int q0 = (blockIdx.x & 63) << 4;
  int r0 = blockIdx.x * 16;                  // == b*S + q0
  int tid = threadIdx.x;
  int w = tid >> 6, lane = tid & 63;
  int lr = lane & 15, lg = lane >> 4;
  int h = w;

  // prefetch MLP W panel 0 (drained at the post-attention barrier)
  stage_tile_swz<256, 64, 8>(Wl, 256, Bp[0], w, lane);

  // ================= attention =================
  const float scale = 0.17677669529663687f;  // 1/sqrt(32)
  bf16x8 aq;
  {
    bf16x8 xq = *(const bf16x8*)(xbf + ((size_t)(b * S_ + q0 + lr)) * D_ + h * DH_ + lg * 8);
#pragma unroll
    for (int j = 0; j < 8; j++) {
      int dj = lg * 8 + j;
      float wq = WQ[((size_t)(layer * H_ + h)) * 1024 + dj * 33];
      float wk = WK[((size_t)(layer * H_ + h)) * 1024 + dj * 33];
      aq[j] = (short)f2bf(bf2f((unsigned short)xq[j]) * wq * wk * scale);
    }
  }
  float dvo[2];
#pragma unroll
  for (int fs = 0; fs < 2; fs++) {
    int fh = fs * 16 + lr;
    int fc = h * DH_ + fh;
    dvo[fs] = WV[((size_t)(layer * H_ + h)) * 1024 + fh * 33] *
              Om[(size_t)layer * 65536 + (size_t)fc * 257];
  }

  f32x4 accPV[2];
  accPV[0] = (f32x4){0.f, 0.f, 0.f, 0.f};
  accPV[1] = (f32x4){0.f, 0.f, 0.f, 0.f};
  float rsum[4] = {0.f, 0.f, 0.f, 0.f};

  const unsigned short* xk_base = xbf + ((size_t)b * S_) * D_ + h * DH_ + lg * 8;
  const unsigned short* vT_base = xnT + ((size_t)(b * D_ + h * DH_)) * S_;

  bf16x8 qkb[4];
#pragma unroll
  for (int c = 0; c < 4; c++)
    qkb[c] = *(const bf16x8*)(xk_base + (size_t)(c * 16 + lr) * D_);

  for (int kt = 0; kt < 16; kt++) {
    int k0 = kt * 64;
    bf16x8 pvb[2][2];
#pragma unroll
    for (int fs = 0; fs < 2; fs++)
#pragma unroll
      for (int kc = 0; kc < 2; kc++)
        pvb[fs][kc] = *(const bf16x8*)(vT_base + (size_t)(fs * 16 + lr) * S_ +
                                       k0 + kc * 32 + lg * 8);
    f32x4 s[4];
#pragma unroll
    for (int c = 0; c < 4; c++)
      s[c] = __builtin_amdgcn_mfma_f32_16x16x32_bf16(aq, qkb[c],
                (f32x4){0.f, 0.f, 0.f, 0.f}, 0, 0, 0);
    int ktn = kt < 15 ? kt + 1 : 15;
#pragma unroll
    for (int c = 0; c < 4; c++)
      qkb[c] = *(const bf16x8*)(xk_base + (size_t)(ktn * 64 + c * 16 + lr) * D_);
#pragma unroll
    for (int c = 0; c < 4; c++)
#pragma unroll
      for (int r = 0; r < 4; r++) {
        float p = __expf(s[c][r]);
        rsum[r] += p;
        P_lds[w][lg * 4 + r][c * 16 + lr] = f2bf(p);
      }
#pragma unroll
    for (int kc = 0; kc < 2; kc++) {
      bf16x8 pa = *(const bf16x8*)(&P_lds[w][lr][kc * 32 + lg * 8]);
#pragma unroll
      for (int fs = 0; fs < 2; fs++)
        accPV[fs] = __builtin_amdgcn_mfma_f32_16x16x32_bf16(pa, pvb[fs][kc],
                       accPV[fs], 0, 0, 0);
    }
  }

  float inv[4];
#pragma unroll
  for (int r = 0; r < 4; r++) {
    float v = rsum[r];
    v += __shfl_xor(v, 1, 64);
    v += __shfl_xor(v, 2, 64);
    v += __shfl_xor(v, 4, 64);
    v += __shfl_xor(v, 8, 64);
    inv[r] = 1.f / v;
  }
  // attention out -> LDS Aa (swizzled [16][256], BKB=512)
#pragma unroll
  for (int fs = 0; fs < 2; fs++)
#pragma unroll
    for (int r = 0; r < 4; r++) {
      float val = accPV[fs][r] * inv[r] * dvo[fs];
      int row = lg * 4 + r, col = h * DH_ + fs * 16 + lr;
      int byte = (row * 512 + col * 2) ^ ((row & 7) << 4);
      *(unsigned short*)((char*)Aa + byte) = f2bf(val);
    }
  __syncthreads();   // Aa visible to all waves; W panel 0 drained

  // ================= MLP: 12 panels (3 gemms x 4 k-steps), prefetch pipeline ====
  int lr16 = lr;
  f32x4 acc[2];
  acc[0] = (f32x4){0.f, 0.f, 0.f, 0.f};
  acc[1] = (f32x4){0.f, 0.f, 0.f, 0.f};
  const unsigned short* Asrc = Aa;

  for (int p = 0; p < 12; ++p) {
    if (p < 11) {
      int pn = p + 1;
      stage_tile_swz<256, 64, 8>(Wl + (size_t)(pn >> 2) * 65536 + (pn & 3) * 64,
                                 256, Bp[pn & 1], w, lane);
    }
    int kk0 = (p & 3) * 64;
#pragma unroll
    for (int kk = 0; kk < 64; kk += 32) {
      bf16x8 a = lds_frag<512>(Asrc, lr16, (kk0 + kk) * 2 + lg * 16);
#pragma unroll
      for (int j = 0; j < 2; j++) {
        bf16x8 bfg = lds_frag<128>(Bp[p & 1], w * 32 + j * 16 + lr16, kk * 2 + lg * 16);
        acc[j] = __builtin_amdgcn_mfma_f32_16x16x32_bf16(a, bfg, acc[j], 0, 0, 0);
      }
    }
    if (p == 3 || p == 7) {
      const float* bias = (p == 3) ? b1 : b2;
      unsigned short* dst = (p == 3) ? Ab : Ab2;
#pragma unroll
      for (int j = 0; j < 2; j++) {
        int col = w * 32 + j * 16 + lr16;
        float bv = bias[col];
#pragma unroll
        for (int r = 0; r < 4; r++) {
          float v = acc[j][r] + bv;
          v = 0.5f * v * (1.f + erff(v * 0.70710678118654752f));
          int row = lg * 4 + r;
          int byte = (row * 512 + col * 2) ^ ((row & 7) << 4);
          *(unsigned short*)((char*)dst + byte) = f2bf(v);
        }
      }
      acc[0] = (f32x4){0.f, 0.f, 0.f, 0.f};
      acc[1] = (f32x4){0.f, 0.f, 0.f, 0.f};
      Asrc = (p == 3) ? Ab : Ab2;
    }
    __syncthreads();
  }

  // ---- final epilogue: bias3 + residual (+ next-layer LN dual emit) ----
#pragma unroll
  for (int j = 0; j < 2; j++) {
    int col = w * 32 + j * 16 + lr16;
    float bv = b3[col];
#pragma unroll
    for (int r = 0; r < 4; r++) {
      int row = lg * 4 + r; int grow = r0 + row;
      float v = acc[j][r] + bv + x[(size_t)grow * D_ + col];
      if constexpr (LAST) {
        actB[(size_t)grow * D_ + col] = f2bf(v);
      } else {
        x[(size_t)grow * D_ + col] = v;
        xf[row][col] = v;
      }
    }
  }

  if constexpr (!LAST) {
    __syncthreads();
#pragma unroll
    for (int rr = 0; rr < 2; rr++) {
      int row = w * 2 + rr; int grow = r0 + row;
      f32x4 v = *(const f32x4*)&xf[row][lane * 4];
      float s = v[0] + v[1] + v[2] + v[3];
      float ss = v[0]*v[0] + v[1]*v[1] + v[2]*v[2] + v[3]*v[3];
#pragma unroll
      for (int off = 1; off < 64; off <<= 1) {
        s  += __shfl_xor(s, off, 64);
        ss += __shfl_xor(ss, off, 64);
      }
      float mean = s * (1.f / D_);
      float var = ss * (1.f / D_) - mean * mean;
      float rinv = rsqrtf(var + 1e-5f);
      float4 g4 = *(const float4*)(lngN + lane * 4);
      float4 b4 = *(const float4*)(lnbN + lane * 4);
      ushort4 o;
      o.x = f2bf((v[0] - mean) * rinv * g4.x + b4.x);
      o.y = f2bf((v[1] - mean) * rinv * g4.y + b4.y);
      o.z = f2bf((v[2] - mean) * rinv * g4.z + b4.z);
      o.w = f2bf((v[3] - mean) * rinv * g4.w + b4.w);
      *(ushort4*)(xbfN + (size_t)grow * D_ + lane * 4) = o;
      if (lane == 0) { mrow[row] = mean; rrow[row] = rinv; }
    }
    __syncthreads();
    int d = tid & 255, half = tid >> 8;
    float gd = lngN[d], bd = lnbN[d];
    int bb = r0 >> 10, s0 = r0 & 1023;
    bf16x8 o8;
#pragma unroll
    for (int k = 0; k < 8; k++) {
      int srow = half * 8 + k;
      o8[k] = (short)f2bf((xf[srow][d] - mrow[srow]) * rrow[srow] * gd + bd);
    }
    *(bf16x8*)(xnTN + ((size_t)(bb * 256 + d)) * S_ + s0 + half * 8) = o8;
  }
}

// ---------------- logits GEMM v4: 500 blocks x 256 thr, 2 blocks/CU ----------------
// Block = 64-col slab (XCD-chunked: adjacent slabs on the same XCD for DRAM page
// locality) x 128 A-tiles of 32 rows. B transposed+converted once into 32KB LDS,
// hoisted to registers; A double-buffered in 2x16KB. Total LDS 64KB -> 2 blocks/CU,
// so the per-iter barrier's store-drain overlaps the co-resident block's compute.
__global__ __launch_bounds__(256) void k_logits(
    const unsigned short* __restrict__ A,    // bf16 [4096][256]
    const float* __restrict__ logitW,        // f32 [256][32000]
    float* __restrict__ C) {
  __shared__ __align__(16) unsigned short Bs[64 * 256];     // 32 KB (init only)
  __shared__ __align__(16) unsigned short As[2][32 * 256];  // 2 x 16 KB

  int tid = threadIdx.x, lane = tid & 63, w = tid >> 6;   // 4 waves
  int wm = w >> 1, wn = w & 1;                            // 2 (rows) x 2 (cols)
  int lr = lane & 15, lg = lane >> 4;

  // XCD-chunked bijective slab map: 500 slabs, xcd 0-3 get 63, xcd 4-7 get 62
  int id = blockIdx.x;
  int xcd = id & 7, s = id >> 3;
  int base = xcd < 4 ? xcd * 63 : 252 + (xcd - 4) * 62;
  int bn0 = (base + s) * 64;

  // issue A tile 0 stage first (async; latency hides under the B-stage)
  stage_tile_swz<32, 256, 4>(A, 256, As[0], w, lane);

  // B-stage: transpose + convert logitW -> Bs [row=v][k] bf16, swizzled (BKB=512)
  {
    int c = tid & 63;           // col within slab (v - bn0)
    int kp = tid >> 6;          // 0..3
    for (int it = 0; it < 32; ++it) {
      int k = it * 8 + kp * 2;
      float f0 = logitW[(size_t)k * V_ + bn0 + c];
      float f1 = logitW[(size_t)(k + 1) * V_ + bn0 + c];
      unsigned pack = (unsigned)f2bf(f0) | ((unsigned)f2bf(f1) << 16);
      int byte = (c * 512 + k * 2) ^ ((c & 7) << 4);
      *(unsigned*)((char*)Bs + byte) = pack;
    }
  }
  __syncthreads();   // Bs + As[0] ready

  // hoist B fragments to registers (constant across all 128 t-iterations)
  bf16x8 breg[2][8];
#pragma unroll
  for (int j = 0; j < 2; j++)
#pragma unroll
    for (int ks = 0; ks < 8; ks++)
      breg[j][ks] = lds_frag<512>(Bs, wn * 32 + j * 16 + lr, ks * 64 + lg * 16);

  for (int t = 0; t < 128; ++t) {
    int cur = t & 1;
    if (t < 127)
      stage_tile_swz<32, 256, 4>(A + (size_t)(t + 1) * 32 * 256, 256, As[cur ^ 1], w, lane);

    f32x4 acc[2];
    acc[0] = (f32x4){0.f, 0.f, 0.f, 0.f};
    acc[1] = (f32x4){0.f, 0.f, 0.f, 0.f};

#pragma unroll
    for (int ks = 0; ks < 8; ks++) {
      bf16x8 af = lds_frag<512>(As[cur], wm * 16 + lr, ks * 64 + lg * 16);
      // swapped operands: lane = A-row (lr), regs = 4 vocab cols
#pragma unroll
      for (int j = 0; j < 2; j++)
        acc[j] = __builtin_amdgcn_mfma_f32_16x16x32_bf16(breg[j][ks], af, acc[j], 0, 0, 0);
    }

    int row = t * 32 + wm * 16 + lr;
#pragma unroll
    for (int j = 0; j < 2; j++) {
      int colb = bn0 + wn * 32 + j * 16 + lg * 4;
      *(f32x4*)(C + (size_t)row * V_ + colb) = acc[j];
    }
    __syncthreads();   // next A buffer staged; prev reads done
  }
}

// ---------------- transpose + f32->bf16 convert (MLP weights) ----------------
__device__ __forceinline__ void tconv_tile(const float* __restrict__ in,
                                           unsigned short* __restrict__ out,
                                           int R, int C, int r0, int c0, int t) {
  __shared__ float tile[64][65];
#pragma unroll
  for (int i = 0; i < 16; i++) {
    int idx = i * 256 + t;
    int lr = idx >> 6, lc = idx & 63;
    tile[lr][lc] = in[(size_t)(r0 + lr) * C + c0 + lc];
  }
  __syncthreads();
#pragma unroll
  for (int i = 0; i < 16; i++) {
    int idx = i * 256 + t;
    int lr = idx >> 6, lc = idx & 63;
    out[(size_t)(c0 + lr) * R + r0 + lc] = f2bf(tile[lc][lr]);
  }
}

__global__ __launch_bounds__(256) void k_tconv_mlp(const float* __restrict__ w1,
                                                   const float* __restrict__ w2,
                                                   const float* __restrict__ w3,
                                                   unsigned short* __restrict__ out) {
  int z = blockIdx.z; int l = z / 3, mm = z % 3;
  const float* in = (mm == 0 ? w1 : mm == 1 ? w2 : w3) + (size_t)l * 65536;
  tconv_tile(in, out + (size_t)z * 65536, 256, 256, blockIdx.y * 64, blockIdx.x * 64, threadIdx.x);
}

// ---------------- launch ----------------
extern "C" void kernel_launch(void* const* d_in, const int* in_sizes, int n_in,
                              void* d_out, int out_size, void* d_ws, size_t ws_size,
                              hipStream_t stream) {
  const int*   X      = (const int*)d_in[0];
  const float* emb    = (const float*)d_in[1];
  const float* WQ     = (const float*)d_in[2];
  const float* WK     = (const float*)d_in[3];
  const float* WV     = (const float*)d_in[4];
  const float* Om     = (const float*)d_in[5];
  const float* lng    = (const float*)d_in[6];
  const float* lnb    = (const float*)d_in[7];
  const float* w1     = (const float*)d_in[8];
  const float* b1     = (const float*)d_in[9];
  const float* w2     = (const float*)d_in[10];
  const float* b2     = (const float*)d_in[11];
  const float* w3     = (const float*)d_in[12];
  const float* b3     = (const float*)d_in[13];
  const float* logitW = (const float*)d_in[14];
  float* out = (float*)d_out;
  char* ws = (char*)d_ws;

  constexpr size_t MB = 1024u * 1024;
  float* x  = (float*)(ws);                                    // 4 MB
  unsigned short* xbf0 = (unsigned short*)(ws + 4 * MB);       // 2 MB
  unsigned short* xbf1 = (unsigned short*)(ws + 6 * MB);       // 2 MB
  unsigned short* xnT0 = (unsigned short*)(ws + 8 * MB);       // 2 MB
  unsigned short* xnT1 = (unsigned short*)(ws + 10 * MB);      // 2 MB
  unsigned short* actB = (unsigned short*)(ws + 12 * MB);      // 2 MB
  unsigned short* mlpW = (unsigned short*)(ws + 14 * MB);      // 1.5 MB

  // MLP weight conversion only (logits W transposed in-kernel)
  k_tconv_mlp<<<dim3(4, 4, 12), 256, 0, stream>>>(w1, w2, w3, mlpW);

  k_embln<<<256, 512, 0, stream>>>(X, emb, lng, lnb, x, xbf0, xnT0);

  for (int l = 0; l < L_; l++) {
    const unsigned short* xbfI = (l & 1) ? xbf1 : xbf0;
    const unsigned short* xnTI = (l & 1) ? xnT1 : xnT0;
    unsigned short* xbfO = (l & 1) ? xbf0 : xbf1;
    unsigned short* xnTO = (l & 1) ? xnT0 : xnT1;
    if (l < L_ - 1) {
      k_layer<0><<<256, 512, 0, stream>>>(
          xbfI, xnTI, WQ, WK, WV, Om, mlpW + (size_t)(l * 3) * 65536,
          b1 + (size_t)l * D_, b2 + (size_t)l * D_, b3 + (size_t)l * D_, x,
          lng + (size_t)(l + 1) * D_, lnb + (size_t)(l + 1) * D_,
          xbfO, xnTO, nullptr, l);
    } else {
      k_layer<1><<<256, 512, 0, stream>>>(
          xbfI, xnTI, WQ, WK, WV, Om, mlpW + (size_t)(l * 3) * 65536,
          b1 + (size_t)l * D_, b2 + (size_t)l * D_, b3 + (size_t)l * D_, x,
          nullptr, nullptr, nullptr, nullptr, actB, l);
    }
  }

  // logits: 500 blocks (2/CU), XCD-chunked col slabs, B-in-registers
  k_logits<<<500, 256, 0, stream>>>(actB, logitW, out);
}

// Round 15
// 349.611 us; speedup vs baseline: 1.0435x; 1.0435x over previous
//
#include <hip/hip_runtime.h>
#include <hip/hip_bf16.h>
#include <cstdint>
#include <cstddef>

#define B_ 4
#define S_ 1024
#define V_ 32000
#define D_ 256
#define H_ 8
#define DH_ 32
#define L_ 4
#define MROWS (B_*S_)

typedef __attribute__((ext_vector_type(8))) short bf16x8;
typedef __attribute__((ext_vector_type(4))) float f32x4;

__device__ __forceinline__ unsigned short f2bf(float f) {
  union { float f; unsigned u; } c; c.f = f;
  unsigned u = c.u;
  u += 0x7fff + ((u >> 16) & 1);   // round-to-nearest-even
  return (unsigned short)(u >> 16);
}
__device__ __forceinline__ float bf2f(unsigned short u) {
  union { unsigned u; float f; } c; c.u = ((unsigned)u) << 16; return c.f;
}

// async global->LDS, 16B per lane; LDS dest is wave-uniform base + lane*16
__device__ __forceinline__ void gload16(const unsigned short* g, unsigned short* l) {
  __builtin_amdgcn_global_load_lds(
      (const __attribute__((address_space(1))) void*)g,
      (__attribute__((address_space(3))) void*)l, 16, 0, 0);
}

// ---- XOR-swizzled LDS tiles: lds[row][inner ^ ((row&7)<<4)] = g[row][inner]
template<int BM, int BK, int NW>
__device__ __forceinline__ void stage_tile_swz(const unsigned short* __restrict__ g, int ldg,
                                               unsigned short* lds, int wave, int lane) {
  constexpr int CH  = BM * BK * 2 / 1024;   // 1KB chunks
  constexpr int BKB = BK * 2;               // bytes per row
#pragma unroll
  for (int t = 0; t < CH / NW; ++t) {
    int c = wave + t * NW;
    int byte  = c * 1024 + lane * 16;
    int row   = byte / BKB;
    int inner = (byte % BKB) ^ ((row & 7) << 4);
    gload16(g + (size_t)row * ldg + (inner >> 1), lds + c * 512);
  }
}

// swizzled 16B fragment read: row-major [*][BKB/2] tile, kbytes multiple of 16
template<int BKB>
__device__ __forceinline__ bf16x8 lds_frag(const unsigned short* base, int row, int kbytes) {
  int b = (row * BKB + kbytes) ^ ((row & 7) << 4);
  return *(const bf16x8*)((const char*)base + b);
}

// ---------------- embed + LN(layer0) + dual-layout emit ----------------
__global__ __launch_bounds__(512) void k_embln(
    const int* __restrict__ X, const float* __restrict__ emb,
    const float* __restrict__ lng, const float* __restrict__ lnb,
    float* __restrict__ x, unsigned short* __restrict__ xbf,
    unsigned short* __restrict__ xnT) {
  __shared__ __align__(16) float xf[16][264];
  __shared__ float mrow[16], rrow[16];
  int r0 = blockIdx.x * 16;
  int tid = threadIdx.x;
  int w = tid >> 6, lane = tid & 63;
#pragma unroll
  for (int rr = 0; rr < 2; rr++) {
    int row = w * 2 + rr; int grow = r0 + row;
    int tok = X[grow];
    f32x4 v = *(const f32x4*)(emb + (size_t)tok * D_ + lane * 4);
    *(f32x4*)(x + (size_t)grow * D_ + lane * 4) = v;
    *(f32x4*)&xf[row][lane * 4] = v;
    float s = v[0] + v[1] + v[2] + v[3];
    float ss = v[0]*v[0] + v[1]*v[1] + v[2]*v[2] + v[3]*v[3];
#pragma unroll
    for (int off = 1; off < 64; off <<= 1) {
      s  += __shfl_xor(s, off, 64);
      ss += __shfl_xor(ss, off, 64);
    }
    float mean = s * (1.f / D_);
    float var = ss * (1.f / D_) - mean * mean;
    float rinv = rsqrtf(var + 1e-5f);
    float4 g4 = *(const float4*)(lng + lane * 4);
    float4 b4 = *(const float4*)(lnb + lane * 4);
    ushort4 o;
    o.x = f2bf((v[0] - mean) * rinv * g4.x + b4.x);
    o.y = f2bf((v[1] - mean) * rinv * g4.y + b4.y);
    o.z = f2bf((v[2] - mean) * rinv * g4.z + b4.z);
    o.w = f2bf((v[3] - mean) * rinv * g4.w + b4.w);
    *(ushort4*)(xbf + (size_t)grow * D_ + lane * 4) = o;
    if (lane == 0) { mrow[row] = mean; rrow[row] = rinv; }
  }
  __syncthreads();
  int d = tid & 255, half = tid >> 8;
  float gd = lng[d], bd = lnb[d];
  int bb = r0 >> 10, s0 = r0 & 1023;
  bf16x8 o8;
#pragma unroll
  for (int k = 0; k < 8; k++) {
    int srow = half * 8 + k;
    o8[k] = (short)f2bf((xf[srow][d] - mrow[srow]) * rrow[srow] * gd + bd);
  }
  *(bf16x8*)(xnT + ((size_t)(bb * 256 + d)) * S_ + s0 + half * 8) = o8;
}

// ---------------- fused layer: attn + 3-GEMM MLP (direct-W register reads) ----------
// 256 blocks x 512 thr. W fragments read straight from L2-resident global (no Bp
// LDS panel, no per-panel barriers/drains). Only 2 barriers in the MLP (Ab, Ab2
// handoffs). K-order unchanged (ascending 32-steps) -> bit-identical output.
template<int LAST>
__global__ __launch_bounds__(512) void k_layer(
    const unsigned short* __restrict__ xbf,   // layer input  [4096][256] bf16
    const unsigned short* __restrict__ xnT,   // layer input  [4][256][1024] bf16
    const float* __restrict__ WQ, const float* __restrict__ WK,
    const float* __restrict__ WV, const float* __restrict__ Om,
    const unsigned short* __restrict__ Wl,    // 3 x [256 n][256 k] bf16 (this layer)
    const float* __restrict__ b1, const float* __restrict__ b2, const float* __restrict__ b3,
    float* __restrict__ x,                    // residual f32
    const float* __restrict__ lngN, const float* __restrict__ lnbN,
    unsigned short* __restrict__ xbfN, unsigned short* __restrict__ xnTN,  // outputs (!LAST)
    unsigned short* __restrict__ actB,        // output (LAST)
    int layer) {
  __shared__ __align__(16) unsigned short P_lds[8][16][72];
  __shared__ __align__(16) unsigned short Aa[16 * 256];
  __shared__ __align__(16) unsigned short Ab[16 * 256];
  __shared__ __align__(16) unsigned short Ab2[16 * 256];
  __shared__ __align__(16) float xf[16][264];
  __shared__ float mrow[16], rrow[16];

  int b = blockIdx.x >> 6;
  int q0 = (blockIdx.x & 63) << 4;
  int r0 = blockIdx.x * 16;                  // == b*S + q0
  int tid = threadIdx.x;
  int w = tid >> 6, lane = tid & 63;
  int lr = lane & 15, lg = lane >> 4;
  int h = w;

  // ================= attention =================
  const float scale = 0.17677669529663687f;  // 1/sqrt(32)
  bf16x8 aq;
  {
    bf16x8 xq = *(const bf16x8*)(xbf + ((size_t)(b * S_ + q0 + lr)) * D_ + h * DH_ + lg * 8);
#pragma unroll
    for (int j = 0; j < 8; j++) {
      int dj = lg * 8 + j;
      float wq = WQ[((size_t)(layer * H_ + h)) * 1024 + dj * 33];
      float wk = WK[((size_t)(layer * H_ + h)) * 1024 + dj * 33];
      aq[j] = (short)f2bf(bf2f((unsigned short)xq[j]) * wq * wk * scale);
    }
  }
  float dvo[2];
#pragma unroll
  for (int fs = 0; fs < 2; fs++) {
    int fh = fs * 16 + lr;
    int fc = h * DH_ + fh;
    dvo[fs] = WV[((size_t)(layer * H_ + h)) * 1024 + fh * 33] *
              Om[(size_t)layer * 65536 + (size_t)fc * 257];
  }

  f32x4 accPV[2];
  accPV[0] = (f32x4){0.f, 0.f, 0.f, 0.f};
  accPV[1] = (f32x4){0.f, 0.f, 0.f, 0.f};
  float rsum[4] = {0.f, 0.f, 0.f, 0.f};

  const unsigned short* xk_base = xbf + ((size_t)b * S_) * D_ + h * DH_ + lg * 8;
  const unsigned short* vT_base = xnT + ((size_t)(b * D_ + h * DH_)) * S_;

  bf16x8 qkb[4];
#pragma unroll
  for (int c = 0; c < 4; c++)
    qkb[c] = *(const bf16x8*)(xk_base + (size_t)(c * 16 + lr) * D_);

  for (int kt = 0; kt < 16; kt++) {
    int k0 = kt * 64;
    bf16x8 pvb[2][2];
#pragma unroll
    for (int fs = 0; fs < 2; fs++)
#pragma unroll
      for (int kc = 0; kc < 2; kc++)
        pvb[fs][kc] = *(const bf16x8*)(vT_base + (size_t)(fs * 16 + lr) * S_ +
                                       k0 + kc * 32 + lg * 8);
    f32x4 s[4];
#pragma unroll
    for (int c = 0; c < 4; c++)
      s[c] = __builtin_amdgcn_mfma_f32_16x16x32_bf16(aq, qkb[c],
                (f32x4){0.f, 0.f, 0.f, 0.f}, 0, 0, 0);
    int ktn = kt < 15 ? kt + 1 : 15;
#pragma unroll
    for (int c = 0; c < 4; c++)
      qkb[c] = *(const bf16x8*)(xk_base + (size_t)(ktn * 64 + c * 16 + lr) * D_);
#pragma unroll
    for (int c = 0; c < 4; c++)
#pragma unroll
      for (int r = 0; r < 4; r++) {
        float p = __expf(s[c][r]);
        rsum[r] += p;
        P_lds[w][lg * 4 + r][c * 16 + lr] = f2bf(p);
      }
#pragma unroll
    for (int kc = 0; kc < 2; kc++) {
      bf16x8 pa = *(const bf16x8*)(&P_lds[w][lr][kc * 32 + lg * 8]);
#pragma unroll
      for (int fs = 0; fs < 2; fs++)
        accPV[fs] = __builtin_amdgcn_mfma_f32_16x16x32_bf16(pa, pvb[fs][kc],
                       accPV[fs], 0, 0, 0);
    }
  }

  float inv[4];
#pragma unroll
  for (int r = 0; r < 4; r++) {
    float v = rsum[r];
    v += __shfl_xor(v, 1, 64);
    v += __shfl_xor(v, 2, 64);
    v += __shfl_xor(v, 4, 64);
    v += __shfl_xor(v, 8, 64);
    inv[r] = 1.f / v;
  }
  // attention out -> LDS Aa (swizzled [16][256], BKB=512)
#pragma unroll
  for (int fs = 0; fs < 2; fs++)
#pragma unroll
    for (int r = 0; r < 4; r++) {
      float val = accPV[fs][r] * inv[r] * dvo[fs];
      int row = lg * 4 + r, col = h * DH_ + fs * 16 + lr;
      int byte = (row * 512 + col * 2) ^ ((row & 7) << 4);
      *(unsigned short*)((char*)Aa + byte) = f2bf(val);
    }
  __syncthreads();   // Aa visible to all waves

  // ================= MLP: 3 GEMMs, W fragments direct from global ====
  f32x4 acc[2];
  const unsigned short* Wp;

  // gemm helper: acc = Asrc(16x256 LDS swizzled) @ Wp[n][k]^T, barrier-free
#define MLP_MM(Asrc, WPTR)                                                        \
  acc[0] = (f32x4){0.f, 0.f, 0.f, 0.f};                                           \
  acc[1] = (f32x4){0.f, 0.f, 0.f, 0.f};                                           \
  Wp = (WPTR);                                                                    \
  _Pragma("unroll")                                                               \
  for (int k0 = 0; k0 < 256; k0 += 32) {                                          \
    bf16x8 a = lds_frag<512>(Asrc, lr, k0 * 2 + lg * 16);                         \
    _Pragma("unroll")                                                             \
    for (int j = 0; j < 2; j++) {                                                 \
      bf16x8 bfg = *(const bf16x8*)(Wp + (size_t)(w * 32 + j * 16 + lr) * 256 +   \
                                    k0 + lg * 8);                                 \
      acc[j] = __builtin_amdgcn_mfma_f32_16x16x32_bf16(a, bfg, acc[j], 0, 0, 0);  \
    }                                                                             \
  }

#define EPI_GELU(bias, dst)                                                       \
  _Pragma("unroll")                                                               \
  for (int j = 0; j < 2; j++) {                                                   \
    int col = w * 32 + j * 16 + lr;                                               \
    float bv = (bias)[col];                                                       \
    _Pragma("unroll")                                                             \
    for (int r = 0; r < 4; r++) {                                                 \
      float v = acc[j][r] + bv;                                                   \
      v = 0.5f * v * (1.f + erff(v * 0.70710678118654752f));                      \
      int row = lg * 4 + r;                                                       \
      int byte = (row * 512 + col * 2) ^ ((row & 7) << 4);                        \
      *(unsigned short*)((char*)(dst) + byte) = f2bf(v);                          \
    }                                                                             \
  }

  MLP_MM(Aa, Wl)
  EPI_GELU(b1, Ab)
  __syncthreads();
  MLP_MM(Ab, Wl + 65536)
  EPI_GELU(b2, Ab2)
  __syncthreads();
  MLP_MM(Ab2, Wl + 2 * 65536)

  // ---- final epilogue: bias3 + residual (+ next-layer LN dual emit) ----
#pragma unroll
  for (int j = 0; j < 2; j++) {
    int col = w * 32 + j * 16 + lr;
    float bv = b3[col];
#pragma unroll
    for (int r = 0; r < 4; r++) {
      int row = lg * 4 + r; int grow = r0 + row;
      float v = acc[j][r] + bv + x[(size_t)grow * D_ + col];
      if constexpr (LAST) {
        actB[(size_t)grow * D_ + col] = f2bf(v);
      } else {
        x[(size_t)grow * D_ + col] = v;
        xf[row][col] = v;
      }
    }
  }

  if constexpr (!LAST) {
    __syncthreads();
#pragma unroll
    for (int rr = 0; rr < 2; rr++) {
      int row = w * 2 + rr; int grow = r0 + row;
      f32x4 v = *(const f32x4*)&xf[row][lane * 4];
      float s = v[0] + v[1] + v[2] + v[3];
      float ss = v[0]*v[0] + v[1]*v[1] + v[2]*v[2] + v[3]*v[3];
#pragma unroll
      for (int off = 1; off < 64; off <<= 1) {
        s  += __shfl_xor(s, off, 64);
        ss += __shfl_xor(ss, off, 64);
      }
      float mean = s * (1.f / D_);
      float var = ss * (1.f / D_) - mean * mean;
      float rinv = rsqrtf(var + 1e-5f);
      float4 g4 = *(const float4*)(lngN + lane * 4);
      float4 b4 = *(const float4*)(lnbN + lane * 4);
      ushort4 o;
      o.x = f2bf((v[0] - mean) * rinv * g4.x + b4.x);
      o.y = f2bf((v[1] - mean) * rinv * g4.y + b4.y);
      o.z = f2bf((v[2] - mean) * rinv * g4.z + b4.z);
      o.w = f2bf((v[3] - mean) * rinv * g4.w + b4.w);
      *(ushort4*)(xbfN + (size_t)grow * D_ + lane * 4) = o;
      if (lane == 0) { mrow[row] = mean; rrow[row] = rinv; }
    }
    __syncthreads();
    int d = tid & 255, half = tid >> 8;
    float gd = lngN[d], bd = lnbN[d];
    int bb = r0 >> 10, s0 = r0 & 1023;
    bf16x8 o8;
#pragma unroll
    for (int k = 0; k < 8; k++) {
      int srow = half * 8 + k;
      o8[k] = (short)f2bf((xf[srow][d] - mrow[srow]) * rrow[srow] * gd + bd);
    }
    *(bf16x8*)(xnTN + ((size_t)(bb * 256 + d)) * S_ + s0 + half * 8) = o8;
  }
#undef MLP_MM
#undef EPI_GELU
}

// ---------------- logits GEMM (round-13 best): B-in-registers persistent ----------
__global__ __launch_bounds__(512) void k_logits(
    const unsigned short* __restrict__ A,    // bf16 [4096][256]
    const float* __restrict__ logitW,        // f32 [256][32000]
    float* __restrict__ C) {
  __shared__ __align__(16) unsigned short Bs[128 * 256];    // 64 KB (stage only)
  __shared__ __align__(16) unsigned short As[2][64 * 256];  // 2 x 32 KB

  int tid = threadIdx.x, lane = tid & 63, w = tid >> 6;
  int wm = w >> 2, wn = w & 3;               // 2 (row-groups) x 4 (col-groups)
  int lr = lane & 15, lg = lane >> 4;
  int bn0 = blockIdx.x * 128;

  // issue A tile 0 stage first (async; latency hides under the B-stage)
  stage_tile_swz<64, 256, 8>(A, 256, As[0], w, lane);

  // B-stage: transpose + convert logitW -> Bs [row=v][k] bf16, swizzled (BKB=512)
  {
    int c = tid & 127;          // col within slab (v - bn0)
    int kp = tid >> 7;          // 0..3
    for (int it = 0; it < 32; ++it) {
      int k = it * 8 + kp * 2;
      float f0 = logitW[(size_t)k * V_ + bn0 + c];
      float f1 = logitW[(size_t)(k + 1) * V_ + bn0 + c];
      unsigned pack = (unsigned)f2bf(f0) | ((unsigned)f2bf(f1) << 16);
      int byte = (c * 512 + k * 2) ^ ((c & 7) << 4);
      *(unsigned*)((char*)Bs + byte) = pack;
    }
  }
  __syncthreads();

  // hoist B fragments to registers (constant across all 64 t-iterations)
  bf16x8 breg[2][8];
#pragma unroll
  for (int j = 0; j < 2; j++)
#pragma unroll
    for (int ks = 0; ks < 8; ks++)
      breg[j][ks] = lds_frag<512>(Bs, wn * 32 + j * 16 + lr, ks * 64 + lg * 16);

  for (int t = 0; t < 64; ++t) {
    int cur = t & 1;
    if (t < 63)
      stage_tile_swz<64, 256, 8>(A + (size_t)(t + 1) * 64 * 256, 256, As[cur ^ 1], w, lane);

    f32x4 acc[2][2];
#pragma unroll
    for (int i = 0; i < 2; i++)
#pragma unroll
      for (int j = 0; j < 2; j++) acc[i][j] = (f32x4){0.f, 0.f, 0.f, 0.f};

#pragma unroll
    for (int ks = 0; ks < 8; ks++) {
      bf16x8 af[2];
#pragma unroll
      for (int i = 0; i < 2; i++)
        af[i] = lds_frag<512>(As[cur], wm * 32 + i * 16 + lr, ks * 64 + lg * 16);
      // swapped operands: lane = A-row (lr), regs = 4 vocab cols
#pragma unroll
      for (int i = 0; i < 2; i++)
#pragma unroll
        for (int j = 0; j < 2; j++)
          acc[i][j] = __builtin_amdgcn_mfma_f32_16x16x32_bf16(breg[j][ks], af[i], acc[i][j], 0, 0, 0);
    }

    int r0 = t * 64;
#pragma unroll
    for (int i = 0; i < 2; i++)
#pragma unroll
      for (int j = 0; j < 2; j++) {
        int row = r0 + wm * 32 + i * 16 + lr;
        int colb = bn0 + wn * 32 + j * 16 + lg * 4;
        __builtin_nontemporal_store(acc[i][j], (f32x4*)(C + (size_t)row * V_ + colb));
      }
    __syncthreads();   // next A buffer staged; prev reads done
  }
}

// ---------------- transpose + f32->bf16 convert (MLP weights) ----------------
__device__ __forceinline__ void tconv_tile(const float* __restrict__ in,
                                           unsigned short* __restrict__ out,
                                           int R, int C, int r0, int c0, int t) {
  __shared__ float tile[64][65];
#pragma unroll
  for (int i = 0; i < 16; i++) {
    int idx = i * 256 + t;
    int lr = idx >> 6, lc = idx & 63;
    tile[lr][lc] = in[(size_t)(r0 + lr) * C + c0 + lc];
  }
  __syncthreads();
#pragma unroll
  for (int i = 0; i < 16; i++) {
    int idx = i * 256 + t;
    int lr = idx >> 6, lc = idx & 63;
    out[(size_t)(c0 + lr) * R + r0 + lc] = f2bf(tile[lc][lr]);
  }
}

__global__ __launch_bounds__(256) void k_tconv_mlp(const float* __restrict__ w1,
                                                   const float* __restrict__ w2,
                                                   const float* __restrict__ w3,
                                                   unsigned short* __restrict__ out) {
  int z = blockIdx.z; int l = z / 3, mm = z % 3;
  const float* in = (mm == 0 ? w1 : mm == 1 ? w2 : w3) + (size_t)l * 65536;
  tconv_tile(in, out + (size_t)z * 65536, 256, 256, blockIdx.y * 64, blockIdx.x * 64, threadIdx.x);
}

// ---------------- launch ----------------
extern "C" void kernel_launch(void* const* d_in, const int* in_sizes, int n_in,
                              void* d_out, int out_size, void* d_ws, size_t ws_size,
                              hipStream_t stream) {
  const int*   X      = (const int*)d_in[0];
  const float* emb    = (const float*)d_in[1];
  const float* WQ     = (const float*)d_in[2];
  const float* WK     = (const float*)d_in[3];
  const float* WV     = (const float*)d_in[4];
  const float* Om     = (const float*)d_in[5];
  const float* lng    = (const float*)d_in[6];
  const float* lnb    = (const float*)d_in[7];
  const float* w1     = (const float*)d_in[8];
  const float* b1     = (const float*)d_in[9];
  const float* w2     = (const float*)d_in[10];
  const float* b2     = (const float*)d_in[11];
  const float* w3     = (const float*)d_in[12];
  const float* b3     = (const float*)d_in[13];
  const float* logitW = (const float*)d_in[14];
  float* out = (float*)d_out;
  char* ws = (char*)d_ws;

  constexpr size_t MB = 1024u * 1024;
  float* x  = (float*)(ws);                                    // 4 MB
  unsigned short* xbf0 = (unsigned short*)(ws + 4 * MB);       // 2 MB
  unsigned short* xbf1 = (unsigned short*)(ws + 6 * MB);       // 2 MB
  unsigned short* xnT0 = (unsigned short*)(ws + 8 * MB);       // 2 MB
  unsigned short* xnT1 = (unsigned short*)(ws + 10 * MB);      // 2 MB
  unsigned short* actB = (unsigned short*)(ws + 12 * MB);      // 2 MB
  unsigned short* mlpW = (unsigned short*)(ws + 14 * MB);      // 1.5 MB

  // MLP weight conversion only (logits W transposed in-kernel)
  k_tconv_mlp<<<dim3(4, 4, 12), 256, 0, stream>>>(w1, w2, w3, mlpW);

  k_embln<<<256, 512, 0, stream>>>(X, emb, lng, lnb, x, xbf0, xnT0);

  for (int l = 0; l < L_; l++) {
    const unsigned short* xbfI = (l & 1) ? xbf1 : xbf0;
    const unsigned short* xnTI = (l & 1) ? xnT1 : xnT0;
    unsigned short* xbfO = (l & 1) ? xbf0 : xbf1;
    unsigned short* xnTO = (l & 1) ? xnT0 : xnT1;
    if (l < L_ - 1) {
      k_layer<0><<<256, 512, 0, stream>>>(
          xbfI, xnTI, WQ, WK, WV, Om, mlpW + (size_t)(l * 3) * 65536,
          b1 + (size_t)l * D_, b2 + (size_t)l * D_, b3 + (size_t)l * D_, x,
          lng + (size_t)(l + 1) * D_, lnb + (size_t)(l + 1) * D_,
          xbfO, xnTO, nullptr, l);
    } else {
      k_layer<1><<<256, 512, 0, stream>>>(
          xbfI, xnTI, WQ, WK, WV, Om, mlpW + (size_t)(l * 3) * 65536,
          b1 + (size_t)l * D_, b2 + (size_t)l * D_, b3 + (size_t)l * D_, x,
          nullptr, nullptr, nullptr, nullptr, actB, l);
    }
  }

  // logits: round-13 best (250 blocks, B-in-registers, nt stores)
  k_logits<<<250, 512, 0, stream>>>(actB, logitW, out);
}

// Round 16
// 332.872 us; speedup vs baseline: 1.0960x; 1.0503x over previous
//
#include <hip/hip_runtime.h>
#include <hip/hip_bf16.h>
#include <cstdint>
#include <cstddef>

#define B_ 4
#define S_ 1024
#define V_ 32000
#define D_ 256
#define H_ 8
#define DH_ 32
#define L_ 4
#define MROWS (B_*S_)

typedef __attribute__((ext_vector_type(8))) short bf16x8;
typedef __attribute__((ext_vector_type(4))) float f32x4;

__device__ __forceinline__ unsigned short f2bf(float f) {
  union { float f; unsigned u; } c; c.f = f;
  unsigned u = c.u;
  u += 0x7fff + ((u >> 16) & 1);   // round-to-nearest-even
  return (unsigned short)(u >> 16);
}
__device__ __forceinline__ float bf2f(unsigned short u) {
  union { unsigned u; float f; } c; c.u = ((unsigned)u) << 16; return c.f;
}

// async global->LDS, 16B per lane; LDS dest is wave-uniform base + lane*16
__device__ __forceinline__ void gload16(const unsigned short* g, unsigned short* l) {
  __builtin_amdgcn_global_load_lds(
      (const __attribute__((address_space(1))) void*)g,
      (__attribute__((address_space(3))) void*)l, 16, 0, 0);
}

// ---- XOR-swizzled LDS tiles: lds[row][inner ^ ((row&7)<<4)] = g[row][inner]
template<int BM, int BK, int NW>
__device__ __forceinline__ void stage_tile_swz(const unsigned short* __restrict__ g, int ldg,
                                               unsigned short* lds, int wave, int lane) {
  constexpr int CH  = BM * BK * 2 / 1024;   // 1KB chunks
  constexpr int BKB = BK * 2;               // bytes per row
#pragma unroll
  for (int t = 0; t < CH / NW; ++t) {
    int c = wave + t * NW;
    int byte  = c * 1024 + lane * 16;
    int row   = byte / BKB;
    int inner = (byte % BKB) ^ ((row & 7) << 4);
    gload16(g + (size_t)row * ldg + (inner >> 1), lds + c * 512);
  }
}

// swizzled 16B fragment read: row-major [*][BKB/2] tile, kbytes multiple of 16
template<int BKB>
__device__ __forceinline__ bf16x8 lds_frag(const unsigned short* base, int row, int kbytes) {
  int b = (row * BKB + kbytes) ^ ((row & 7) << 4);
  return *(const bf16x8*)((const char*)base + b);
}

// ---------------- embed + LN(layer0) + dual-layout emit ----------------
__global__ __launch_bounds__(512) void k_embln(
    const int* __restrict__ X, const float* __restrict__ emb,
    const float* __restrict__ lng, const float* __restrict__ lnb,
    float* __restrict__ x, unsigned short* __restrict__ xbf,
    unsigned short* __restrict__ xnT) {
  __shared__ __align__(16) float xf[16][264];
  __shared__ float mrow[16], rrow[16];
  int r0 = blockIdx.x * 16;
  int tid = threadIdx.x;
  int w = tid >> 6, lane = tid & 63;
#pragma unroll
  for (int rr = 0; rr < 2; rr++) {
    int row = w * 2 + rr; int grow = r0 + row;
    int tok = X[grow];
    f32x4 v = *(const f32x4*)(emb + (size_t)tok * D_ + lane * 4);
    *(f32x4*)(x + (size_t)grow * D_ + lane * 4) = v;
    *(f32x4*)&xf[row][lane * 4] = v;
    float s = v[0] + v[1] + v[2] + v[3];
    float ss = v[0]*v[0] + v[1]*v[1] + v[2]*v[2] + v[3]*v[3];
#pragma unroll
    for (int off = 1; off < 64; off <<= 1) {
      s  += __shfl_xor(s, off, 64);
      ss += __shfl_xor(ss, off, 64);
    }
    float mean = s * (1.f / D_);
    float var = ss * (1.f / D_) - mean * mean;
    float rinv = rsqrtf(var + 1e-5f);
    float4 g4 = *(const float4*)(lng + lane * 4);
    float4 b4 = *(const float4*)(lnb + lane * 4);
    ushort4 o;
    o.x = f2bf((v[0] - mean) * rinv * g4.x + b4.x);
    o.y = f2bf((v[1] - mean) * rinv * g4.y + b4.y);
    o.z = f2bf((v[2] - mean) * rinv * g4.z + b4.z);
    o.w = f2bf((v[3] - mean) * rinv * g4.w + b4.w);
    *(ushort4*)(xbf + (size_t)grow * D_ + lane * 4) = o;
    if (lane == 0) { mrow[row] = mean; rrow[row] = rinv; }
  }
  __syncthreads();
  int d = tid & 255, half = tid >> 8;
  float gd = lng[d], bd = lnb[d];
  int bb = r0 >> 10, s0 = r0 & 1023;
  bf16x8 o8;
#pragma unroll
  for (int k = 0; k < 8; k++) {
    int srow = half * 8 + k;
    o8[k] = (short)f2bf((xf[srow][d] - mrow[srow]) * rrow[srow] * gd + bd);
  }
  *(bf16x8*)(xnT + ((size_t)(bb * 256 + d)) * S_ + s0 + half * 8) = o8;
}

// ---------------- fused layer (round-13 best): attn + 3-GEMM MLP -----------------
template<int LAST>
__global__ __launch_bounds__(512) void k_layer(
    const unsigned short* __restrict__ xbf,   // layer input  [4096][256] bf16
    const unsigned short* __restrict__ xnT,   // layer input  [4][256][1024] bf16
    const float* __restrict__ WQ, const float* __restrict__ WK,
    const float* __restrict__ WV, const float* __restrict__ Om,
    const unsigned short* __restrict__ Wl,    // 3 x [256][256] bf16 (this layer)
    const float* __restrict__ b1, const float* __restrict__ b2, const float* __restrict__ b3,
    float* __restrict__ x,                    // residual f32
    const float* __restrict__ lngN, const float* __restrict__ lnbN,
    unsigned short* __restrict__ xbfN, unsigned short* __restrict__ xnTN,  // outputs (!LAST)
    unsigned short* __restrict__ actB,        // output (LAST)
    int layer) {
  __shared__ __align__(16) unsigned short P_lds[8][16][72];
  __shared__ __align__(16) unsigned short Aa[16 * 256];
  __shared__ __align__(16) unsigned short Ab[16 * 256];
  __shared__ __align__(16) unsigned short Ab2[16 * 256];
  __shared__ __align__(16) unsigned short Bp[2][256 * 64];
  __shared__ __align__(16) float xf[16][264];
  __shared__ float mrow[16], rrow[16];

  int b = blockIdx.x >> 6;
  int q0 = (blockIdx.x & 63) << 4;
  int r0 = blockIdx.x * 16;                  // == b*S + q0
  int tid = threadIdx.x;
  int w = tid >> 6, lane = tid & 63;
  int lr = lane & 15, lg = lane >> 4;
  int h = w;

  // prefetch MLP W panel 0 (drained at the post-attention barrier)
  stage_tile_swz<256, 64, 8>(Wl, 256, Bp[0], w, lane);

  // ================= attention =================
  const float scale = 0.17677669529663687f;  // 1/sqrt(32)
  bf16x8 aq;
  {
    bf16x8 xq = *(const bf16x8*)(xbf + ((size_t)(b * S_ + q0 + lr)) * D_ + h * DH_ + lg * 8);
#pragma unroll
    for (int j = 0; j < 8; j++) {
      int dj = lg * 8 + j;
      float wq = WQ[((size_t)(layer * H_ + h)) * 1024 + dj * 33];
      float wk = WK[((size_t)(layer * H_ + h)) * 1024 + dj * 33];
      aq[j] = (short)f2bf(bf2f((unsigned short)xq[j]) * wq * wk * scale);
    }
  }
  float dvo[2];
#pragma unroll
  for (int fs = 0; fs < 2; fs++) {
    int fh = fs * 16 + lr;
    int fc = h * DH_ + fh;
    dvo[fs] = WV[((size_t)(layer * H_ + h)) * 1024 + fh * 33] *
              Om[(size_t)layer * 65536 + (size_t)fc * 257];
  }

  f32x4 accPV[2];
  accPV[0] = (f32x4){0.f, 0.f, 0.f, 0.f};
  accPV[1] = (f32x4){0.f, 0.f, 0.f, 0.f};
  float rsum[4] = {0.f, 0.f, 0.f, 0.f};

  const unsigned short* xk_base = xbf + ((size_t)b * S_) * D_ + h * DH_ + lg * 8;
  const unsigned short* vT_base = xnT + ((size_t)(b * D_ + h * DH_)) * S_;

  bf16x8 qkb[4];
#pragma unroll
  for (int c = 0; c < 4; c++)
    qkb[c] = *(const bf16x8*)(xk_base + (size_t)(c * 16 + lr) * D_);

  for (int kt = 0; kt < 16; kt++) {
    int k0 = kt * 64;
    bf16x8 pvb[2][2];
#pragma unroll
    for (int fs = 0; fs < 2; fs++)
#pragma unroll
      for (int kc = 0; kc < 2; kc++)
        pvb[fs][kc] = *(const bf16x8*)(vT_base + (size_t)(fs * 16 + lr) * S_ +
                                       k0 + kc * 32 + lg * 8);
    f32x4 s[4];
#pragma unroll
    for (int c = 0; c < 4; c++)
      s[c] = __builtin_amdgcn_mfma_f32_16x16x32_bf16(aq, qkb[c],
                (f32x4){0.f, 0.f, 0.f, 0.f}, 0, 0, 0);
    int ktn = kt < 15 ? kt + 1 : 15;
#pragma unroll
    for (int c = 0; c < 4; c++)
      qkb[c] = *(const bf16x8*)(xk_base + (size_t)(ktn * 64 + c * 16 + lr) * D_);
#pragma unroll
    for (int c = 0; c < 4; c++)
#pragma unroll
      for (int r = 0; r < 4; r++) {
        float p = __expf(s[c][r]);
        rsum[r] += p;
        P_lds[w][lg * 4 + r][c * 16 + lr] = f2bf(p);
      }
#pragma unroll
    for (int kc = 0; kc < 2; kc++) {
      bf16x8 pa = *(const bf16x8*)(&P_lds[w][lr][kc * 32 + lg * 8]);
#pragma unroll
      for (int fs = 0; fs < 2; fs++)
        accPV[fs] = __builtin_amdgcn_mfma_f32_16x16x32_bf16(pa, pvb[fs][kc],
                       accPV[fs], 0, 0, 0);
    }
  }

  float inv[4];
#pragma unroll
  for (int r = 0; r < 4; r++) {
    float v = rsum[r];
    v += __shfl_xor(v, 1, 64);
    v += __shfl_xor(v, 2, 64);
    v += __shfl_xor(v, 4, 64);
    v += __shfl_xor(v, 8, 64);
    inv[r] = 1.f / v;
  }
  // attention out -> LDS Aa (swizzled [16][256], BKB=512)
#pragma unroll
  for (int fs = 0; fs < 2; fs++)
#pragma unroll
    for (int r = 0; r < 4; r++) {
      float val = accPV[fs][r] * inv[r] * dvo[fs];
      int row = lg * 4 + r, col = h * DH_ + fs * 16 + lr;
      int byte = (row * 512 + col * 2) ^ ((row & 7) << 4);
      *(unsigned short*)((char*)Aa + byte) = f2bf(val);
    }
  __syncthreads();   // Aa visible to all waves; W panel 0 drained

  // ================= MLP: 12 panels (3 gemms x 4 k-steps), prefetch pipeline ====
  int lr16 = lr;
  f32x4 acc[2];
  acc[0] = (f32x4){0.f, 0.f, 0.f, 0.f};
  acc[1] = (f32x4){0.f, 0.f, 0.f, 0.f};
  const unsigned short* Asrc = Aa;

  for (int p = 0; p < 12; ++p) {
    if (p < 11) {
      int pn = p + 1;
      stage_tile_swz<256, 64, 8>(Wl + (size_t)(pn >> 2) * 65536 + (pn & 3) * 64,
                                 256, Bp[pn & 1], w, lane);
    }
    int kk0 = (p & 3) * 64;
#pragma unroll
    for (int kk = 0; kk < 64; kk += 32) {
      bf16x8 a = lds_frag<512>(Asrc, lr16, (kk0 + kk) * 2 + lg * 16);
#pragma unroll
      for (int j = 0; j < 2; j++) {
        bf16x8 bfg = lds_frag<128>(Bp[p & 1], w * 32 + j * 16 + lr16, kk * 2 + lg * 16);
        acc[j] = __builtin_amdgcn_mfma_f32_16x16x32_bf16(a, bfg, acc[j], 0, 0, 0);
      }
    }
    if (p == 3 || p == 7) {
      const float* bias = (p == 3) ? b1 : b2;
      unsigned short* dst = (p == 3) ? Ab : Ab2;
#pragma unroll
      for (int j = 0; j < 2; j++) {
        int col = w * 32 + j * 16 + lr16;
        float bv = bias[col];
#pragma unroll
        for (int r = 0; r < 4; r++) {
          float v = acc[j][r] + bv;
          v = 0.5f * v * (1.f + erff(v * 0.70710678118654752f));
          int row = lg * 4 + r;
          int byte = (row * 512 + col * 2) ^ ((row & 7) << 4);
          *(unsigned short*)((char*)dst + byte) = f2bf(v);
        }
      }
      acc[0] = (f32x4){0.f, 0.f, 0.f, 0.f};
      acc[1] = (f32x4){0.f, 0.f, 0.f, 0.f};
      Asrc = (p == 3) ? Ab : Ab2;
    }
    __syncthreads();
  }

  // ---- final epilogue: bias3 + residual (+ next-layer LN dual emit) ----
#pragma unroll
  for (int j = 0; j < 2; j++) {
    int col = w * 32 + j * 16 + lr16;
    float bv = b3[col];
#pragma unroll
    for (int r = 0; r < 4; r++) {
      int row = lg * 4 + r; int grow = r0 + row;
      float v = acc[j][r] + bv + x[(size_t)grow * D_ + col];
      if constexpr (LAST) {
        actB[(size_t)grow * D_ + col] = f2bf(v);
      } else {
        x[(size_t)grow * D_ + col] = v;
        xf[row][col] = v;
      }
    }
  }

  if constexpr (!LAST) {
    __syncthreads();
#pragma unroll
    for (int rr = 0; rr < 2; rr++) {
      int row = w * 2 + rr; int grow = r0 + row;
      f32x4 v = *(const f32x4*)&xf[row][lane * 4];
      float s = v[0] + v[1] + v[2] + v[3];
      float ss = v[0]*v[0] + v[1]*v[1] + v[2]*v[2] + v[3]*v[3];
#pragma unroll
      for (int off = 1; off < 64; off <<= 1) {
        s  += __shfl_xor(s, off, 64);
        ss += __shfl_xor(ss, off, 64);
      }
      float mean = s * (1.f / D_);
      float var = ss * (1.f / D_) - mean * mean;
      float rinv = rsqrtf(var + 1e-5f);
      float4 g4 = *(const float4*)(lngN + lane * 4);
      float4 b4 = *(const float4*)(lnbN + lane * 4);
      ushort4 o;
      o.x = f2bf((v[0] - mean) * rinv * g4.x + b4.x);
      o.y = f2bf((v[1] - mean) * rinv * g4.y + b4.y);
      o.z = f2bf((v[2] - mean) * rinv * g4.z + b4.z);
      o.w = f2bf((v[3] - mean) * rinv * g4.w + b4.w);
      *(ushort4*)(xbfN + (size_t)grow * D_ + lane * 4) = o;
      if (lane == 0) { mrow[row] = mean; rrow[row] = rinv; }
    }
    __syncthreads();
    int d = tid & 255, half = tid >> 8;
    float gd = lngN[d], bd = lnbN[d];
    int bb = r0 >> 10, s0 = r0 & 1023;
    bf16x8 o8;
#pragma unroll
    for (int k = 0; k < 8; k++) {
      int srow = half * 8 + k;
      o8[k] = (short)f2bf((xf[srow][d] - mrow[srow]) * rrow[srow] * gd + bd);
    }
    *(bf16x8*)(xnTN + ((size_t)(bb * 256 + d)) * S_ + s0 + half * 8) = o8;
  }
}

// ---------------- logits GEMM: B-in-registers + T4 counted-vmcnt barrier ----------
// 250 blocks x 512 thr. Per iter each wave issues 4 gload16 (next A tile) then 4
// C-stores. s_waitcnt vmcnt(4) retires the OLDEST ops (= loads(t+1) + prior store
// backlog) and leaves this iter's 4 stores in flight across the raw s_barrier --
// store drain overlaps the next iteration's ds_read+MFMA instead of serializing.
__global__ __launch_bounds__(512) void k_logits(
    const unsigned short* __restrict__ A,    // bf16 [4096][256]
    const float* __restrict__ logitW,        // f32 [256][32000]
    float* __restrict__ C) {
  __shared__ __align__(16) unsigned short Bs[128 * 256];    // 64 KB (stage only)
  __shared__ __align__(16) unsigned short As[2][64 * 256];  // 2 x 32 KB

  int tid = threadIdx.x, lane = tid & 63, w = tid >> 6;
  int wm = w >> 2, wn = w & 3;               // 2 (row-groups) x 4 (col-groups)
  int lr = lane & 15, lg = lane >> 4;
  int bn0 = blockIdx.x * 128;

  // issue A tile 0 stage first (async; latency hides under the B-stage)
  stage_tile_swz<64, 256, 8>(A, 256, As[0], w, lane);

  // B-stage: transpose + convert logitW -> Bs [row=v][k] bf16, swizzled (BKB=512)
  {
    int c = tid & 127;          // col within slab (v - bn0)
    int kp = tid >> 7;          // 0..3
    for (int it = 0; it < 32; ++it) {
      int k = it * 8 + kp * 2;
      float f0 = logitW[(size_t)k * V_ + bn0 + c];
      float f1 = logitW[(size_t)(k + 1) * V_ + bn0 + c];
      unsigned pack = (unsigned)f2bf(f0) | ((unsigned)f2bf(f1) << 16);
      int byte = (c * 512 + k * 2) ^ ((c & 7) << 4);
      *(unsigned*)((char*)Bs + byte) = pack;
    }
  }
  __syncthreads();   // full drain once: Bs + As[0] ready

  // hoist B fragments to registers (constant across all 64 t-iterations)
  bf16x8 breg[2][8];
#pragma unroll
  for (int j = 0; j < 2; j++)
#pragma unroll
    for (int ks = 0; ks < 8; ks++)
      breg[j][ks] = lds_frag<512>(Bs, wn * 32 + j * 16 + lr, ks * 64 + lg * 16);

  for (int t = 0; t < 64; ++t) {
    int cur = t & 1;
    if (t < 63)
      stage_tile_swz<64, 256, 8>(A + (size_t)(t + 1) * 64 * 256, 256, As[cur ^ 1], w, lane);

    f32x4 acc[2][2];
#pragma unroll
    for (int i = 0; i < 2; i++)
#pragma unroll
      for (int j = 0; j < 2; j++) acc[i][j] = (f32x4){0.f, 0.f, 0.f, 0.f};

#pragma unroll
    for (int ks = 0; ks < 8; ks++) {
      bf16x8 af[2];
#pragma unroll
      for (int i = 0; i < 2; i++)
        af[i] = lds_frag<512>(As[cur], wm * 32 + i * 16 + lr, ks * 64 + lg * 16);
      // swapped operands: lane = A-row (lr), regs = 4 vocab cols
#pragma unroll
      for (int i = 0; i < 2; i++)
#pragma unroll
        for (int j = 0; j < 2; j++)
          acc[i][j] = __builtin_amdgcn_mfma_f32_16x16x32_bf16(breg[j][ks], af[i], acc[i][j], 0, 0, 0);
    }

    int r0 = t * 64;
#pragma unroll
    for (int i = 0; i < 2; i++)
#pragma unroll
      for (int j = 0; j < 2; j++) {
        int row = r0 + wm * 32 + i * 16 + lr;
        int colb = bn0 + wn * 32 + j * 16 + lg * 4;
        __builtin_nontemporal_store(acc[i][j], (f32x4*)(C + (size_t)row * V_ + colb));
      }

    // T4: wait own loads(t+1) (oldest), leave this iter's 4 stores in flight
    asm volatile("s_waitcnt vmcnt(4)" ::: "memory");
    __builtin_amdgcn_sched_barrier(0);
    __builtin_amdgcn_s_barrier();
  }
}

// ---------------- transpose + f32->bf16 convert (MLP weights) ----------------
__device__ __forceinline__ void tconv_tile(const float* __restrict__ in,
                                           unsigned short* __restrict__ out,
                                           int R, int C, int r0, int c0, int t) {
  __shared__ float tile[64][65];
#pragma unroll
  for (int i = 0; i < 16; i++) {
    int idx = i * 256 + t;
    int lr = idx >> 6, lc = idx & 63;
    tile[lr][lc] = in[(size_t)(r0 + lr) * C + c0 + lc];
  }
  __syncthreads();
#pragma unroll
  for (int i = 0; i < 16; i++) {
    int idx = i * 256 + t;
    int lr = idx >> 6, lc = idx & 63;
    out[(size_t)(c0 + lr) * R + r0 + lc] = f2bf(tile[lc][lr]);
  }
}

__global__ __launch_bounds__(256) void k_tconv_mlp(const float* __restrict__ w1,
                                                   const float* __restrict__ w2,
                                                   const float* __restrict__ w3,
                                                   unsigned short* __restrict__ out) {
  int z = blockIdx.z; int l = z / 3, mm = z % 3;
  const float* in = (mm == 0 ? w1 : mm == 1 ? w2 : w3) + (size_t)l * 65536;
  tconv_tile(in, out + (size_t)z * 65536, 256, 256, blockIdx.y * 64, blockIdx.x * 64, threadIdx.x);
}

// ---------------- launch ----------------
extern "C" void kernel_launch(void* const* d_in, const int* in_sizes, int n_in,
                              void* d_out, int out_size, void* d_ws, size_t ws_size,
                              hipStream_t stream) {
  const int*   X      = (const int*)d_in[0];
  const float* emb    = (const float*)d_in[1];
  const float* WQ     = (const float*)d_in[2];
  const float* WK     = (const float*)d_in[3];
  const float* WV     = (const float*)d_in[4];
  const float* Om     = (const float*)d_in[5];
  const float* lng    = (const float*)d_in[6];
  const float* lnb    = (const float*)d_in[7];
  const float* w1     = (const float*)d_in[8];
  const float* b1     = (const float*)d_in[9];
  const float* w2     = (const float*)d_in[10];
  const float* b2     = (const float*)d_in[11];
  const float* w3     = (const float*)d_in[12];
  const float* b3     = (const float*)d_in[13];
  const float* logitW = (const float*)d_in[14];
  float* out = (float*)d_out;
  char* ws = (char*)d_ws;

  constexpr size_t MB = 1024u * 1024;
  float* x  = (float*)(ws);                                    // 4 MB
  unsigned short* xbf0 = (unsigned short*)(ws + 4 * MB);       // 2 MB
  unsigned short* xbf1 = (unsigned short*)(ws + 6 * MB);       // 2 MB
  unsigned short* xnT0 = (unsigned short*)(ws + 8 * MB);       // 2 MB
  unsigned short* xnT1 = (unsigned short*)(ws + 10 * MB);      // 2 MB
  unsigned short* actB = (unsigned short*)(ws + 12 * MB);      // 2 MB
  unsigned short* mlpW = (unsigned short*)(ws + 14 * MB);      // 1.5 MB

  // MLP weight conversion only (logits W transposed in-kernel)
  k_tconv_mlp<<<dim3(4, 4, 12), 256, 0, stream>>>(w1, w2, w3, mlpW);

  k_embln<<<256, 512, 0, stream>>>(X, emb, lng, lnb, x, xbf0, xnT0);

  for (int l = 0; l < L_; l++) {
    const unsigned short* xbfI = (l & 1) ? xbf1 : xbf0;
    const unsigned short* xnTI = (l & 1) ? xnT1 : xnT0;
    unsigned short* xbfO = (l & 1) ? xbf0 : xbf1;
    unsigned short* xnTO = (l & 1) ? xnT0 : xnT1;
    if (l < L_ - 1) {
      k_layer<0><<<256, 512, 0, stream>>>(
          xbfI, xnTI, WQ, WK, WV, Om, mlpW + (size_t)(l * 3) * 65536,
          b1 + (size_t)l * D_, b2 + (size_t)l * D_, b3 + (size_t)l * D_, x,
          lng + (size_t)(l + 1) * D_, lnb + (size_t)(l + 1) * D_,
          xbfO, xnTO, nullptr, l);
    } else {
      k_layer<1><<<256, 512, 0, stream>>>(
          xbfI, xnTI, WQ, WK, WV, Om, mlpW + (size_t)(l * 3) * 65536,
          b1 + (size_t)l * D_, b2 + (size_t)l * D_, b3 + (size_t)l * D_, x,
          nullptr, nullptr, nullptr, nullptr, actB, l);
    }
  }

  // logits: B-in-registers persistent + counted-vmcnt pipeline
  k_logits<<<250, 512, 0, stream>>>(actB, logitW, out);
}